// Round 4
// baseline (119.828 us; speedup 1.0000x reference)
//
#include <hip/hip_runtime.h>

#define NQ 32768
#define NC 8192
#define CFEAT 128
#define CSPLIT 16
#define TILE (NC / CSPLIT)   // 512 coords per split
#define BLK 128
#define QPT 4                // queries per thread: 1 ds_read_b128 feeds 4 chains
#define QPB (BLK * QPT)      // 512 queries per block

// Phase 1: per-split partial argmin. Each thread owns FOUR query points and
// scans TILE coords staged in LDS. LDS-pipe traffic (the R3 co-limiter:
// ~12 cyc/ds_read_b128 on the shared per-CU pipe) is amortized over 4 query
// chains, dropping it below the ~24 us VALU floor.
//
// Numerics (BIT-EXACT vs harness reference, verified absmax=0.0):
//   t = (-2cx)*px; t = fma(-2cy,py,t); t = fma(-2cz,pz,t); d = cc + t
// (-2 pre-fold is a power-of-2 scale: exact, commutes with round-to-nearest.)
// Strict < with ascending scan order = lowest-index tiebreak, matching argmin.
__global__ __launch_bounds__(BLK) void argmin_part(
    const float* __restrict__ coords, const float* __restrict__ points,
    float* __restrict__ bestd, int* __restrict__ besti) {
  __shared__ float4 sc[TILE];
  const int s = blockIdx.y;
  const int base = s * TILE;
  const int q0 = blockIdx.x * QPB + threadIdx.x;

  // Stage this split's coords into LDS, precomputing (-2c, cc).
  // cc rounding order matches np.sum(coords*coords, -1): ((x*x+y*y)+z*z).
  for (int i = threadIdx.x; i < TILE; i += BLK) {
    const float cx = coords[(base + i) * 3 + 0];
    const float cy = coords[(base + i) * 3 + 1];
    const float cz = coords[(base + i) * 3 + 2];
    const float cc = __fadd_rn(
        __fadd_rn(__fmul_rn(cx, cx), __fmul_rn(cy, cy)), __fmul_rn(cz, cz));
    sc[i] = make_float4(-2.0f * cx, -2.0f * cy, -2.0f * cz, cc);
  }
  __syncthreads();

  float px[QPT], py[QPT], pz[QPT], best[QPT];
  int bi[QPT];
  #pragma unroll
  for (int k = 0; k < QPT; ++k) {
    const int q = q0 + k * BLK;
    px[k] = points[q * 3 + 0];
    py[k] = points[q * 3 + 1];
    pz[k] = points[q * 3 + 2];
    best[k] = __builtin_inff();
    bi[k] = base;
  }

  #pragma unroll 4
  for (int i = 0; i < TILE; ++i) {
    const float4 c = sc[i];  // wave-uniform addr -> LDS broadcast, no conflicts
    const int idx = base + i;
    #pragma unroll
    for (int k = 0; k < QPT; ++k) {
      float t = __fmul_rn(c.x, px[k]);
      t = __fmaf_rn(c.y, py[k], t);
      t = __fmaf_rn(c.z, pz[k], t);
      const float d = __fadd_rn(c.w, t);
      const bool lt = d < best[k];         // strict < : first-index tiebreak
      best[k] = lt ? d : best[k];
      bi[k]   = lt ? idx : bi[k];
    }
  }

  #pragma unroll
  for (int k = 0; k < QPT; ++k) {
    const int q = q0 + k * BLK;
    bestd[s * NQ + q] = best[k];
    besti[s * NQ + q] = bi[k];
  }
}

// Phase 2: reduce the CSPLIT partial candidates per query (ascending split
// order + strict < keeps the lowest index on exact ties), then gather the
// 128-float feature row. 32 threads per query row, float4 each.
__global__ __launch_bounds__(256) void reduce_gather(
    const float* __restrict__ feature, const float* __restrict__ bestd,
    const int* __restrict__ besti, float4* __restrict__ out) {
  const int t = blockIdx.x * 256 + threadIdx.x;
  const int q = t >> 5;
  const int j = t & 31;

  float bd = bestd[q];
  int bi = besti[q];
  #pragma unroll
  for (int s = 1; s < CSPLIT; ++s) {
    const float d = bestd[s * NQ + q];
    const int i2 = besti[s * NQ + q];
    if (d < bd) { bd = d; bi = i2; }
  }
  const float4* frow = (const float4*)(feature + (size_t)bi * CFEAT);
  out[(size_t)q * (CFEAT / 4) + j] = frow[j];
}

extern "C" void kernel_launch(void* const* d_in, const int* in_sizes, int n_in,
                              void* d_out, int out_size, void* d_ws, size_t ws_size,
                              hipStream_t stream) {
  const float* coords  = (const float*)d_in[0];   // [8192, 3]
  const float* feature = (const float*)d_in[1];   // [8192, 128]
  const float* points  = (const float*)d_in[2];   // [32768, 3]
  float* out = (float*)d_out;                     // [32768, 128]

  float* bestd = (float*)d_ws;                    // [CSPLIT * NQ]
  int*   besti = (int*)((char*)d_ws + (size_t)CSPLIT * NQ * sizeof(float));

  dim3 grid1(NQ / QPB, CSPLIT);                   // (64, 16) = 1024 blocks
  argmin_part<<<grid1, BLK, 0, stream>>>(coords, points, bestd, besti);

  const int total = NQ * (CFEAT / 4);             // one thread per float4
  reduce_gather<<<total / 256, 256, 0, stream>>>(feature, bestd, besti,
                                                 (float4*)out);
}

// Round 5
// 112.814 us; speedup vs baseline: 1.0622x; 1.0622x over previous
//
#include <hip/hip_runtime.h>

#define NQ 32768
#define NC 8192
#define CFEAT 128
#define CSPLIT 64
#define TILE (NC / CSPLIT)   // 128 coords per split
#define BLK 256
#define QPT 8                // queries per thread: 1 ds_read_b128 feeds 8 chains
#define QPB (BLK * QPT)      // 2048 queries per block

// ws layout: [0, 256KB) packed u64 per query; [256KB, 384KB) float4 ctab[NC].
#define PACKED_OFF 0
#define CTAB_OFF ((size_t)NQ * 8)

// Init: set per-query packed keys to UINT64_MAX and precompute the coord
// table (-2cx,-2cy,-2cz,cc) once (was redundantly done per block before).
// cc rounding order matches np.sum(coords*coords, -1): ((x*x+y*y)+z*z).
__global__ __launch_bounds__(256) void init_kernel(
    const float* __restrict__ coords, float4* __restrict__ ctab,
    unsigned long long* __restrict__ packed) {
  const int t = blockIdx.x * 256 + threadIdx.x;   // grid covers NQ threads
  packed[t] = ~0ull;
  if (t < NC) {
    const float cx = coords[t * 3 + 0];
    const float cy = coords[t * 3 + 1];
    const float cz = coords[t * 3 + 2];
    const float cc = __fadd_rn(
        __fadd_rn(__fmul_rn(cx, cx), __fmul_rn(cy, cy)), __fmul_rn(cz, cz));
    ctab[t] = make_float4(-2.0f * cx, -2.0f * cy, -2.0f * cz, cc);
  }
}

// Phase 1: per-split partial argmin. Each thread owns EIGHT query points and
// scans TILE coords staged in LDS (one broadcast ds_read_b128 feeds 8 chains
// -> LDS pipe ~10us, below the ~24us VALU floor). CSPLIT=64 keeps 4096 waves
// (16/CU) for TLP — R4 showed 2048 waves (BLK=128) stalls at VALUBusy 50%.
//
// Numerics (BIT-EXACT vs harness reference, verified absmax=0.0):
//   t = (-2cx)*px; t = fma(-2cy,py,t); t = fma(-2cz,pz,t); d = cc + t
// (-2 pre-fold is a power-of-2 scale: exact, commutes with round-to-nearest.)
// Result published via atomicMin on key = (sortable_u32(d)<<32)|idx: the
// float->u32 map (b<0 ? ~b : b|0x80000000) is strictly monotone, so u64-min
// = min distance with lowest-index tiebreak — matches np.argmin exactly,
// independent of split completion order.
__global__ __launch_bounds__(BLK) void argmin_part(
    const float4* __restrict__ ctab, const float* __restrict__ points,
    unsigned long long* __restrict__ packed) {
  __shared__ float4 sc[TILE];
  const int s = blockIdx.y;
  const int base = s * TILE;
  const int q0 = blockIdx.x * QPB + threadIdx.x;

  if (threadIdx.x < TILE) sc[threadIdx.x] = ctab[base + threadIdx.x];
  __syncthreads();

  float px[QPT], py[QPT], pz[QPT], best[QPT];
  int bi[QPT];
  #pragma unroll
  for (int k = 0; k < QPT; ++k) {
    const int q = q0 + k * BLK;
    px[k] = points[q * 3 + 0];
    py[k] = points[q * 3 + 1];
    pz[k] = points[q * 3 + 2];
    best[k] = __builtin_inff();
    bi[k] = base;
  }

  #pragma unroll 4
  for (int i = 0; i < TILE; ++i) {
    const float4 c = sc[i];  // wave-uniform addr -> LDS broadcast, no conflicts
    const int idx = base + i;
    #pragma unroll
    for (int k = 0; k < QPT; ++k) {
      float t = __fmul_rn(c.x, px[k]);
      t = __fmaf_rn(c.y, py[k], t);
      t = __fmaf_rn(c.z, pz[k], t);
      const float d = __fadd_rn(c.w, t);
      const bool lt = d < best[k];         // strict < : first-index tiebreak
      best[k] = lt ? d : best[k];
      bi[k]   = lt ? idx : bi[k];
    }
  }

  #pragma unroll
  for (int k = 0; k < QPT; ++k) {
    const int q = q0 + k * BLK;
    const unsigned b = __float_as_uint(best[k]);
    const unsigned u = (b & 0x80000000u) ? ~b : (b | 0x80000000u);
    const unsigned long long key =
        ((unsigned long long)u << 32) | (unsigned)bi[k];
    atomicMin(&packed[q], key);            // fire-and-forget, device scope
  }
}

// Phase 2: pure gather. 32 threads per query row; low dword of the packed
// key (little-endian) is the winning index.
__global__ __launch_bounds__(256) void gather_feat(
    const float* __restrict__ feature, const unsigned* __restrict__ packed_lo,
    float4* __restrict__ out) {
  const int t = blockIdx.x * 256 + threadIdx.x;
  const int q = t >> 5;
  const int j = t & 31;
  const unsigned idx = packed_lo[2 * q];   // low word = index
  out[(size_t)q * (CFEAT / 4) + j] =
      ((const float4*)feature)[(size_t)idx * (CFEAT / 4) + j];
}

extern "C" void kernel_launch(void* const* d_in, const int* in_sizes, int n_in,
                              void* d_out, int out_size, void* d_ws, size_t ws_size,
                              hipStream_t stream) {
  const float* coords  = (const float*)d_in[0];   // [8192, 3]
  const float* feature = (const float*)d_in[1];   // [8192, 128]
  const float* points  = (const float*)d_in[2];   // [32768, 3]
  float* out = (float*)d_out;                     // [32768, 128]

  unsigned long long* packed =
      (unsigned long long*)((char*)d_ws + PACKED_OFF);
  float4* ctab = (float4*)((char*)d_ws + CTAB_OFF);

  init_kernel<<<NQ / 256, 256, 0, stream>>>(coords, ctab, packed);

  dim3 grid1(NQ / QPB, CSPLIT);                   // (16, 64) = 1024 blocks
  argmin_part<<<grid1, BLK, 0, stream>>>(ctab, points, packed);

  const int total = NQ * (CFEAT / 4);             // one thread per float4
  gather_feat<<<total / 256, 256, 0, stream>>>(feature, (const unsigned*)packed,
                                               (float4*)out);
}

// Round 6
// 110.969 us; speedup vs baseline: 1.0798x; 1.0166x over previous
//
#include <hip/hip_runtime.h>

#define NQ 32768
#define NC 8192
#define CFEAT 128
#define CSPLIT 64
#define TILE (NC / CSPLIT)   // 128 coords per split
#define BLK 256
#define QPT 4                // queries per thread
#define QPB (BLK * QPT)      // 1024 queries per block

// ws layout: [0, 256KB) packed u64 per query; [256KB, 384KB) float4 ctab[NC].
#define PACKED_OFF 0
#define CTAB_OFF ((size_t)NQ * 8)

// Init: set per-query packed keys to UINT64_MAX and precompute the coord
// table (-2cx,-2cy,-2cz,cc) once.
// cc rounding order matches np.sum(coords*coords, -1): ((x*x+y*y)+z*z).
__global__ __launch_bounds__(256) void init_kernel(
    const float* __restrict__ coords, float4* __restrict__ ctab,
    unsigned long long* __restrict__ packed) {
  const int t = blockIdx.x * 256 + threadIdx.x;   // grid covers NQ threads
  packed[t] = ~0ull;
  if (t < NC) {
    const float cx = coords[t * 3 + 0];
    const float cy = coords[t * 3 + 1];
    const float cz = coords[t * 3 + 2];
    const float cc = __fadd_rn(
        __fadd_rn(__fmul_rn(cx, cx), __fmul_rn(cy, cy)), __fmul_rn(cz, cz));
    ctab[t] = make_float4(-2.0f * cx, -2.0f * cy, -2.0f * cz, cc);
  }
}

// Phase 1: per-split partial argmin — NO LDS. ctab[base+i] has a wave-uniform
// address (blockIdx + loop counter), so the compiler scalarizes it into
// batched s_load_dwordx* into SGPRs; each VALU op reads its coord as the one
// allowed SGPR operand. This removes ds_read/syncthreads/lgkmcnt stalls from
// the inner loop (R5's VALUBusy=72% co-limiter). QPT=4 x CSPLIT=64 -> 8192
// waves = 32/CU (R5 had 16/CU); __launch_bounds__(256,8) caps VGPR at 64.
//
// Numerics (BIT-EXACT vs harness reference, verified absmax=0.0):
//   t = (-2cx)*px; t = fma(-2cy,py,t); t = fma(-2cz,pz,t); d = cc + t
// (-2 pre-fold is a power-of-2 scale: exact, commutes with round-to-nearest.)
// Publish via atomicMin on key = (sortable_u32(d)<<32)|idx: monotone float->
// u32 map (b<0 ? ~b : b|0x80000000) makes u64-min = (min d, lowest idx) —
// matches np.argmin exactly, independent of split completion order.
__global__ __launch_bounds__(BLK, 8) void argmin_part(
    const float4* __restrict__ ctab, const float* __restrict__ points,
    unsigned long long* __restrict__ packed) {
  const int s = blockIdx.y;
  const int base = s * TILE;
  const int q0 = blockIdx.x * QPB + threadIdx.x;

  float px[QPT], py[QPT], pz[QPT], best[QPT];
  int bi[QPT];
  #pragma unroll
  for (int k = 0; k < QPT; ++k) {
    const int q = q0 + k * BLK;
    px[k] = points[q * 3 + 0];
    py[k] = points[q * 3 + 1];
    pz[k] = points[q * 3 + 2];
    best[k] = __builtin_inff();
    bi[k] = base;
  }

  #pragma unroll 8
  for (int i = 0; i < TILE; ++i) {
    const float4 c = ctab[base + i];     // wave-uniform -> s_load into SGPRs
    const int idx = base + i;            // uniform -> SGPR operand of cndmask
    #pragma unroll
    for (int k = 0; k < QPT; ++k) {
      float t = __fmul_rn(c.x, px[k]);
      t = __fmaf_rn(c.y, py[k], t);
      t = __fmaf_rn(c.z, pz[k], t);
      const float d = __fadd_rn(c.w, t);
      const bool lt = d < best[k];       // strict < : first-index tiebreak
      best[k] = lt ? d : best[k];
      bi[k]   = lt ? idx : bi[k];
    }
  }

  #pragma unroll
  for (int k = 0; k < QPT; ++k) {
    const int q = q0 + k * BLK;
    const unsigned b = __float_as_uint(best[k]);
    const unsigned u = (b & 0x80000000u) ? ~b : (b | 0x80000000u);
    const unsigned long long key =
        ((unsigned long long)u << 32) | (unsigned)bi[k];
    atomicMin(&packed[q], key);          // fire-and-forget, device scope
  }
}

// Phase 2: pure gather. 32 threads per query row; low dword of the packed
// key (little-endian) is the winning index.
__global__ __launch_bounds__(256) void gather_feat(
    const float* __restrict__ feature, const unsigned* __restrict__ packed_lo,
    float4* __restrict__ out) {
  const int t = blockIdx.x * 256 + threadIdx.x;
  const int q = t >> 5;
  const int j = t & 31;
  const unsigned idx = packed_lo[2 * q];  // low word = index
  out[(size_t)q * (CFEAT / 4) + j] =
      ((const float4*)feature)[(size_t)idx * (CFEAT / 4) + j];
}

extern "C" void kernel_launch(void* const* d_in, const int* in_sizes, int n_in,
                              void* d_out, int out_size, void* d_ws, size_t ws_size,
                              hipStream_t stream) {
  const float* coords  = (const float*)d_in[0];   // [8192, 3]
  const float* feature = (const float*)d_in[1];   // [8192, 128]
  const float* points  = (const float*)d_in[2];   // [32768, 3]
  float* out = (float*)d_out;                     // [32768, 128]

  unsigned long long* packed =
      (unsigned long long*)((char*)d_ws + PACKED_OFF);
  float4* ctab = (float4*)((char*)d_ws + CTAB_OFF);

  init_kernel<<<NQ / 256, 256, 0, stream>>>(coords, ctab, packed);

  dim3 grid1(NQ / QPB, CSPLIT);                   // (32, 64) = 2048 blocks
  argmin_part<<<grid1, BLK, 0, stream>>>(ctab, points, packed);

  const int total = NQ * (CFEAT / 4);             // one thread per float4
  gather_feat<<<total / 256, 256, 0, stream>>>(feature, (const unsigned*)packed,
                                               (float4*)out);
}

// Round 7
// 109.763 us; speedup vs baseline: 1.0917x; 1.0110x over previous
//
#include <hip/hip_runtime.h>

#define NQ 32768
#define NC 8192
#define CFEAT 128
#define CSPLIT 64
#define TILE (NC / CSPLIT)   // 128 coords per split
#define BLK 256
#define QPT 4                // queries per thread
#define QPB (BLK * QPT)      // 1024 queries per block

// ws layout: [0, 8 MB) f32 bestd[NQ][CSPLIT]; then float4 ctab[NC] (128 KB).
#define BESTD_OFF 0
#define CTAB_OFF ((size_t)NQ * CSPLIT * 4)

// Precompute coord table (-2cx,-2cy,-2cz,cc) once.
// cc rounding order matches np.sum(coords*coords, -1): ((x*x+y*y)+z*z).
__global__ __launch_bounds__(256) void init_ctab(
    const float* __restrict__ coords, float4* __restrict__ ctab) {
  const int t = blockIdx.x * 256 + threadIdx.x;   // grid covers NC threads
  const float cx = coords[t * 3 + 0];
  const float cy = coords[t * 3 + 1];
  const float cz = coords[t * 3 + 2];
  const float cc = __fadd_rn(
      __fadd_rn(__fmul_rn(cx, cx), __fmul_rn(cy, cy)), __fmul_rn(cz, cz));
  ctab[t] = make_float4(-2.0f * cx, -2.0f * cy, -2.0f * cz, cc);
}

// Phase 1: per-split min DISTANCE only — no index tracking. This cuts the
// inner loop from 7 VALU/pair (R6: cmp+2 cndmask for the index) to 5
// (mul,fma,fma,add,min) -> 17 us VALU floor. No atomics (R6's 16 MB
// write-through tail): plain stores into bestd[q][s], scattered across lanes
// but absorbed by L2 (8 MB array), fire-and-forget.
//
// Numerics (BIT-EXACT vs harness reference, verified absmax=0.0):
//   t = (-2cx)*px; t = fma(-2cy,py,t); t = fma(-2cz,pz,t); d = cc + t
// (-2 pre-fold is a power-of-2 scale: exact, commutes with round-to-nearest.)
// v_min_f32 over the split preserves the exact bit pattern of the min
// (inputs are finite; min value is order-independent).
__global__ __launch_bounds__(BLK, 8) void argmin_split(
    const float4* __restrict__ ctab, const float* __restrict__ points,
    float* __restrict__ bestd) {
  const int s = blockIdx.y;
  const int base = s * TILE;
  const int q0 = blockIdx.x * QPB + threadIdx.x;

  float px[QPT], py[QPT], pz[QPT], best[QPT];
  #pragma unroll
  for (int k = 0; k < QPT; ++k) {
    const int q = q0 + k * BLK;
    px[k] = points[q * 3 + 0];
    py[k] = points[q * 3 + 1];
    pz[k] = points[q * 3 + 2];
    best[k] = __builtin_inff();
  }

  #pragma unroll 8
  for (int i = 0; i < TILE; ++i) {
    const float4 c = ctab[base + i];     // wave-uniform -> s_load into SGPRs
    #pragma unroll
    for (int k = 0; k < QPT; ++k) {
      float t = __fmul_rn(c.x, px[k]);
      t = __fmaf_rn(c.y, py[k], t);
      t = __fmaf_rn(c.z, pz[k], t);
      const float d = __fadd_rn(c.w, t);
      best[k] = fminf(best[k], d);       // v_min_f32, 1 inst
    }
  }

  #pragma unroll
  for (int k = 0; k < QPT; ++k) {
    const int q = q0 + k * BLK;
    bestd[(size_t)q * CSPLIT + s] = best[k];
  }
}

// Phase 2 (one wave per query, fused): reduce 64 split-mins -> global min +
// lowest winning split (ballot/ffs = lowest lane on value ties); rescan that
// split's 128 coords (bit-exact recompute guarantees an equality hit; first
// match = lowest index). Tiebreak chain == np.argmin's global first-index.
// Then gather the 128-float feature row with 64 lanes x float2.
__global__ __launch_bounds__(256) void rescan_gather(
    const float4* __restrict__ ctab, const float* __restrict__ points,
    const float* __restrict__ bestd, const float* __restrict__ feature,
    float2* __restrict__ out) {
  const int q = blockIdx.x * 4 + (threadIdx.x >> 6);
  const int l = threadIdx.x & 63;

  // lane l holds split l's min — 256 B coalesced read per wave
  const float v = bestd[(size_t)q * CSPLIT + l];
  float m = v;
  #pragma unroll
  for (int off = 32; off; off >>= 1) m = fminf(m, __shfl_xor(m, off, 64));
  const unsigned long long bs = __ballot(v == m);
  const int sstar = __ffsll(bs) - 1;            // lowest split attaining min

  const float px = points[q * 3 + 0];           // wave-uniform
  const float py = points[q * 3 + 1];
  const float pz = points[q * 3 + 2];
  const int base = sstar * TILE;

  const float4 c0 = ctab[base + l];             // coalesced, lanes consecutive
  const float4 c1 = ctab[base + 64 + l];
  float t0 = __fmul_rn(c0.x, px);
  t0 = __fmaf_rn(c0.y, py, t0);
  t0 = __fmaf_rn(c0.z, pz, t0);
  const float d0 = __fadd_rn(c0.w, t0);
  float t1 = __fmul_rn(c1.x, px);
  t1 = __fmaf_rn(c1.y, py, t1);
  t1 = __fmaf_rn(c1.z, pz, t1);
  const float d1 = __fadd_rn(c1.w, t1);

  const unsigned long long b0 = __ballot(d0 == m);
  const unsigned long long b1 = __ballot(d1 == m);
  const int off_in = b0 ? (__ffsll(b0) - 1) : (64 + __ffsll(b1) - 1);
  const int idx = base + off_in;

  const float2* fr = (const float2*)(feature + (size_t)idx * CFEAT);
  out[(size_t)q * (CFEAT / 2) + l] = fr[l];
}

extern "C" void kernel_launch(void* const* d_in, const int* in_sizes, int n_in,
                              void* d_out, int out_size, void* d_ws, size_t ws_size,
                              hipStream_t stream) {
  const float* coords  = (const float*)d_in[0];   // [8192, 3]
  const float* feature = (const float*)d_in[1];   // [8192, 128]
  const float* points  = (const float*)d_in[2];   // [32768, 3]
  float* out = (float*)d_out;                     // [32768, 128]

  float* bestd = (float*)((char*)d_ws + BESTD_OFF);
  float4* ctab = (float4*)((char*)d_ws + CTAB_OFF);

  init_ctab<<<NC / 256, 256, 0, stream>>>(coords, ctab);

  dim3 grid1(NQ / QPB, CSPLIT);                   // (32, 64) = 2048 blocks
  argmin_split<<<grid1, BLK, 0, stream>>>(ctab, points, bestd);

  rescan_gather<<<NQ / 4, 256, 0, stream>>>(ctab, points, bestd, feature,
                                            (float2*)out);
}